// Round 11
// baseline (449.611 us; speedup 1.0000x reference)
//
#include <hip/hip_runtime.h>
#include <math.h>

#define N_TOK 40
#define N1    41      // N_TOK + 1
#define BS    8
#define DD    256     // D
#define HH    256     // H
#define NTRI  10660   // C(41,3)
#define NPAIR 780     // pairs (i,k) with k-i>=2
#define NPTASK (NPAIR * BS)   // 6240 tasks, 16 lanes each
#define ROWF  (BS * N1 * HH)  // 83968 floats per [b][t][h] array
#define MNEG  (-1e38f)
#define DPB   256

// ---- MEASUREMENT ROUND 2 (score & dp): REP factors put each dispatch
// above the 40 µs fill cutoff -> visible in top-5 with own counters.
// phase_time = dur_us / REP. Repeats are idempotent (same stores, same
// values). An opaque-zero offset (inline-asm) inside each rep defeats
// load hoisting so every rep honestly re-executes its memory traffic.
#define SCORE_REP 8
#define DP_REP    8

// ---------------- Kernel 1: projections (R9 TLP version, REP=1)
__global__ __launch_bounds__(1024) void k_proj(
    const float* __restrict__ enc, const float* __restrict__ W1,
    const float* __restrict__ b1v,
    float* __restrict__ P, float* __restrict__ Qb, float* __restrict__ Dd)
{
    const int t  = blockIdx.x;           // 0..40
    const int h  = threadIdx.x & 255;    // 0..255
    const int pr = threadIdx.x >> 8;     // 0..3: b-pair
    const int bA = 2 * pr, bB = 2 * pr + 1;

    __shared__ float e[BS][DD];          // 8 KB
    e[bA][h] = enc[(t * BS + bA) * DD + h];
    e[bB][h] = enc[(t * BS + bB) * DD + h];
    __syncthreads();

    float a0 = 0.f, c0 = 0.f, a1 = 0.f, c1 = 0.f;
    const float* Wp = W1 + h;
    const float* Wq = W1 + DD * HH + h;

    #pragma unroll 8
    for (int d = 0; d < DD; ++d) {
        float wp = Wp[d * HH];
        float wq = Wq[d * HH];
        float e0 = e[bA][d];
        float e1 = e[bB][d];
        a0 = fmaf(e0, wp, a0); c0 = fmaf(e0, wq, c0);
        a1 = fmaf(e1, wp, a1); c1 = fmaf(e1, wq, c1);
    }

    const float bb = b1v[h];
    const int iA = ((bA * N1) + t) * HH + h;
    const int iB = ((bB * N1) + t) * HH + h;
    P[iA]  = a0;          P[iB]  = a1;
    Qb[iA] = c0 + bb;     Qb[iB] = c1 + bb;
    Dd[iA] = a0 - c0;     Dd[iB] = a1 - c1;
}

// ---------------- Kernel 2: per-(i,k)-pair scores (R1 body, REP w/ opaque zero)
__global__ __launch_bounds__(256) void k_score(
    const float* __restrict__ P, const float* __restrict__ Qb,
    const float* __restrict__ Dd, const float* __restrict__ W2,
    const float* __restrict__ b2, float* __restrict__ S)
{
    const int gt   = blockIdx.x * 256 + threadIdx.x;
    const int task = gt >> 4;        // (pair, b), b fastest
    const int t    = gt & 15;

    const int p = task >> 3;         // pair index, w descending
    const int b = task & 7;

    int c = (int)((sqrtf(8.f * (float)p + 1.f) - 1.f) * 0.5f);
    while ((c + 1) * (c + 2) / 2 <= p) ++c;
    while (c * (c + 1) / 2 > p) --c;
    const int w    = 40 - c;
    const int i    = p - c * (c + 1) / 2;
    const int k    = i + w;
    const int nj   = w - 1;
    const int n2   = w - 2;
    const int base = n2 * (n2 + 1) * (119 - 2 * n2) / 6;   // == soff(w)

    float* Sout = S + b * NTRI + base + i * nj;

    for (int rep = 0; rep < SCORE_REP; ++rep) {
        // opaque zero: value is 0 every rep, but hipcc cannot prove it ->
        // all addresses below are loop-variant -> loads re-execute each rep.
        int z = 0;
        asm volatile("" : "+v"(z));

        const float4* Pr  = (const float4*)(P  + z + ((b * N1 + i) << 8)) + t * 4;
        const float4* Qr  = (const float4*)(Qb + z + ((b * N1 + k) << 8)) + t * 4;
        const float4* W2r = (const float4*)(W2 + z) + t * 8;

        float4 pp[4], qq[4], wa[4], wb[4];
        #pragma unroll
        for (int q = 0; q < 4; ++q) {
            pp[q] = Pr[q]; qq[q] = Qr[q];
            wa[q] = W2r[q * 2]; wb[q] = W2r[q * 2 + 1];
        }
        const float bb0 = b2[0], bb1 = b2[1];

        const float4* Drow = (const float4*)(Dd + z + ((b * N1 + i + 1) << 8)) + t * 4;

        for (int jp = 0; jp < nj; ++jp) {
            float s0 = 0.f, s1 = 0.f;
            #pragma unroll
            for (int q = 0; q < 4; ++q) {
                float4 dd = Drow[q];
                float r0 = fmaxf(dd.x + qq[q].x - pp[q].x, 0.f);
                float r1 = fmaxf(dd.y + qq[q].y - pp[q].y, 0.f);
                float r2 = fmaxf(dd.z + qq[q].z - pp[q].z, 0.f);
                float r3 = fmaxf(dd.w + qq[q].w - pp[q].w, 0.f);
                s0 = fmaf(r0, wa[q].x, s0); s1 = fmaf(r0, wa[q].y, s1);
                s0 = fmaf(r1, wa[q].z, s0); s1 = fmaf(r1, wa[q].w, s1);
                s0 = fmaf(r2, wb[q].x, s0); s1 = fmaf(r2, wb[q].y, s1);
                s0 = fmaf(r3, wb[q].z, s0); s1 = fmaf(r3, wb[q].w, s1);
            }
            #pragma unroll
            for (int d = 1; d < 16; d <<= 1) {
                s0 += __shfl_xor(s0, d);
                s1 += __shfl_xor(s1, d);
            }
            if (t == 0) {
                float S0 = s0 + bb0, S1 = s1 + bb1;
                Sout[jp] = fmaxf(S0, S1) + log1pf(__expf(-fabsf(S0 - S1)));
            }
            Drow += 64;
        }
    }
}

// ---------------- Kernel 3: per-batch DP (R0 body, REP w/ opaque zero)
__device__ __forceinline__ int tri_base(int i) { return (i * (81 - i)) >> 1; }
#define BIDX(i, j) (tri_base(i) + ((j) - (i) - 1))

constexpr int soff(int W) {
    int s = 0;
    for (int v = 2; v < W; ++v) s += (N1 - v) * (v - 1);
    return s;
}
constexpr int pick_T(int m, int nj) {
    int T = 1;
    while (T < 16 && m * (T * 2) <= DPB && T < nj) T *= 2;
    return T;
}

template<int W>
__device__ __forceinline__ void dp_step(float* __restrict__ Btri,
                                        const float* __restrict__ Sl, int tid)
{
    constexpr int m    = N1 - W;
    constexpr int nj   = W - 1;
    constexpr int T    = pick_T(m, nj);
    constexpr int CH   = (nj + T - 1) / T;
    constexpr int base = soff(W);

    if (tid < m * T) {
        const int i = tid / T;
        const int h = tid % T;
        const int k = i + W;

        float g[CH];
        #pragma unroll
        for (int q = 0; q < CH; ++q) {
            int jp = h + q * T;
            bool live = (q < CH - 1) || (jp < nj);
            int jj = live ? jp : 0;
            float v = Sl[base + i * nj + jj]
                    + Btri[BIDX(i, i + 1 + jj)]
                    + Btri[BIDX(i + 1 + jj, k)];
            g[q] = live ? v : MNEG;
        }
        float mx = g[0];
        #pragma unroll
        for (int q = 1; q < CH; ++q) mx = fmaxf(mx, g[q]);
        float s = 0.f;
        #pragma unroll
        for (int q = 0; q < CH; ++q) s += __expf(g[q] - mx);
        #pragma unroll
        for (int d = 1; d < T; d <<= 1) {
            float mo = __shfl_xor(mx, d);
            float so = __shfl_xor(s, d);
            float nm = fmaxf(mx, mo);
            s = s * __expf(mx - nm) + so * __expf(mo - nm);
            mx = nm;
        }
        if (h == 0)
            Btri[BIDX(i, k)] = mx + __logf(s);
    }
    __syncthreads();
}

template<int W>
__device__ __forceinline__ void dp_from(float* __restrict__ Btri,
                                        const float* __restrict__ Sl, int tid)
{
    dp_step<W>(Btri, Sl, tid);
    if constexpr (W + 1 <= N_TOK) dp_from<W + 1>(Btri, Sl, tid);
}

__global__ __launch_bounds__(DPB) void k_dp(
    const float* __restrict__ Sg, const int* __restrict__ lengths,
    float* __restrict__ out)
{
    __shared__ __align__(16) float Sl[NTRI];
    __shared__ float Btri[820];
    const int tid = threadIdx.x;
    const int b   = blockIdx.x;

    for (int rep = 0; rep < DP_REP; ++rep) {
        int z = 0;
        asm volatile("" : "+v"(z));   // opaque zero: defeat cross-rep hoisting

        const float4* src = (const float4*)(Sg + z + b * NTRI);
        float4* dst = (float4*)Sl;
        for (int x = tid; x < NTRI / 4; x += DPB) dst[x] = src[x];
        if (tid < N_TOK) Btri[tri_base(tid)] = 0.f;
        __syncthreads();

        dp_from<2>(Btri, Sl, tid);

        if (tid == 0) {
            int L = lengths[b];
            out[b] = Btri[BIDX(0, L)];
        }
        __syncthreads();
    }
}

extern "C" void kernel_launch(void* const* d_in, const int* in_sizes, int n_in,
                              void* d_out, int out_size, void* d_ws, size_t ws_size,
                              hipStream_t stream)
{
    const float* enc = (const float*)d_in[0];
    const float* W1  = (const float*)d_in[1];
    const float* b1  = (const float*)d_in[2];
    const float* W2  = (const float*)d_in[3];
    const float* b2  = (const float*)d_in[4];
    const int* lengths = (const int*)d_in[5];

    float* ws = (float*)d_ws;
    float* P  = ws;
    float* Qb = ws + ROWF;
    float* Dd = ws + 2 * ROWF;
    float* S  = ws + 3 * ROWF;

    k_proj<<<dim3(N1), dim3(1024), 0, stream>>>(enc, W1, b1, P, Qb, Dd);
    k_score<<<dim3(NPTASK * 16 / 256), dim3(256), 0, stream>>>(P, Qb, Dd, W2, b2, S);
    k_dp<<<dim3(BS), dim3(DPB), 0, stream>>>(S, lengths, (float*)d_out);
}

// Round 12
// 123.762 us; speedup vs baseline: 3.6329x; 3.6329x over previous
//
#include <hip/hip_runtime.h>
#include <math.h>

#define N_TOK 40
#define N1    41      // N_TOK + 1
#define BS    8
#define DD    256     // D
#define HH    256     // H
#define NTRI  10660   // C(41,3)
#define NPAIR 780     // pairs (i,k) with k-i>=2
#define NPTASK (NPAIR * BS)   // 6240 tasks, one WAVE each now
#define ROWF  (BS * N1 * HH)  // 83968 floats per [b][t][h] array
#define MNEG  (-1e38f)
#define DPB   256

// ---------------- Kernel 1: projections (R9 TLP version, verbatim)
__global__ __launch_bounds__(1024) void k_proj(
    const float* __restrict__ enc, const float* __restrict__ W1,
    const float* __restrict__ b1v,
    float* __restrict__ P, float* __restrict__ Qb, float* __restrict__ Dd)
{
    const int t  = blockIdx.x;           // 0..40
    const int h  = threadIdx.x & 255;    // 0..255
    const int pr = threadIdx.x >> 8;     // 0..3: b-pair
    const int bA = 2 * pr, bB = 2 * pr + 1;

    __shared__ float e[BS][DD];          // 8 KB
    e[bA][h] = enc[(t * BS + bA) * DD + h];
    e[bB][h] = enc[(t * BS + bB) * DD + h];
    __syncthreads();

    float a0 = 0.f, c0 = 0.f, a1 = 0.f, c1 = 0.f;
    const float* Wp = W1 + h;
    const float* Wq = W1 + DD * HH + h;

    #pragma unroll 8
    for (int d = 0; d < DD; ++d) {
        float wp = Wp[d * HH];
        float wq = Wq[d * HH];
        float e0 = e[bA][d];
        float e1 = e[bB][d];
        a0 = fmaf(e0, wp, a0); c0 = fmaf(e0, wq, c0);
        a1 = fmaf(e1, wp, a1); c1 = fmaf(e1, wq, c1);
    }

    const float bb = b1v[h];
    const int iA = ((bA * N1) + t) * HH + h;
    const int iB = ((bB * N1) + t) * HH + h;
    P[iA]  = a0;          P[iB]  = a1;
    Qb[iA] = c0 + bb;     Qb[iB] = c1 + bb;
    Dd[iA] = a0 - c0;     Dd[iB] = a1 - c1;
}

// ---------------- Kernel 2: scores — ONE WAVE per (pair,b) task.
// R11 measured the 16-lane/serial-j version at 29 µs/pass: VALUBusy 23%,
// Occupancy 7% -> latency-bound, critical path = w=40 wave x 39 serial
// j-iters x ~1800 cyc naked dependent chain. Fix: 4 j-slices x 16 h-lanes
// per wave (critical path 39 -> 10 iters) and 6240 waves in 1560 blocks
// (~6 waves/SIMD TLP hides the rest). Each triple's loads, fmaf order,
// 16-lane shfl_xor reduction (same participants), and t==0 store are
// verbatim R1 -> S bitwise identical.
__global__ __launch_bounds__(256) void k_score(
    const float* __restrict__ P, const float* __restrict__ Qb,
    const float* __restrict__ Dd, const float* __restrict__ W2,
    const float* __restrict__ b2, float* __restrict__ S)
{
    const int task = blockIdx.x * 4 + (threadIdx.x >> 6);  // one wave per task
    const int lane = threadIdx.x & 63;
    const int js   = lane >> 4;      // j-slice 0..3
    const int t    = lane & 15;      // h-chunk, same meaning as before

    const int p = task >> 3;         // pair index, w descending
    const int b = task & 7;

    int c = (int)((sqrtf(8.f * (float)p + 1.f) - 1.f) * 0.5f);
    while ((c + 1) * (c + 2) / 2 <= p) ++c;
    while (c * (c + 1) / 2 > p) --c;
    const int w    = 40 - c;
    const int i    = p - c * (c + 1) / 2;
    const int k    = i + w;
    const int nj   = w - 1;
    const int n2   = w - 2;
    const int base = n2 * (n2 + 1) * (119 - 2 * n2) / 6;   // == soff(w)

    const float4* Pr  = (const float4*)(P  + ((b * N1 + i) << 8)) + t * 4;
    const float4* Qr  = (const float4*)(Qb + ((b * N1 + k) << 8)) + t * 4;
    const float4* W2r = (const float4*)(W2) + t * 8;

    float4 pp[4], qq[4], wa[4], wb[4];
    #pragma unroll
    for (int q = 0; q < 4; ++q) {
        pp[q] = Pr[q]; qq[q] = Qr[q];
        wa[q] = W2r[q * 2]; wb[q] = W2r[q * 2 + 1];
    }
    const float bb0 = b2[0], bb1 = b2[1];
    float* Sout = S + b * NTRI + base + i * nj;

    // j-slice loop: slice js covers jp = js, js+4, ... (guard keeps whole
    // 16-lane groups uniformly active -> shfl groups fully live)
    for (int jp = js; jp < nj; jp += 4) {
        const float4* Drow =
            (const float4*)(Dd + ((b * N1 + i + 1 + jp) << 8)) + t * 4;
        float s0 = 0.f, s1 = 0.f;
        #pragma unroll
        for (int q = 0; q < 4; ++q) {
            float4 dd = Drow[q];
            float r0 = fmaxf(dd.x + qq[q].x - pp[q].x, 0.f);
            float r1 = fmaxf(dd.y + qq[q].y - pp[q].y, 0.f);
            float r2 = fmaxf(dd.z + qq[q].z - pp[q].z, 0.f);
            float r3 = fmaxf(dd.w + qq[q].w - pp[q].w, 0.f);
            s0 = fmaf(r0, wa[q].x, s0); s1 = fmaf(r0, wa[q].y, s1);
            s0 = fmaf(r1, wa[q].z, s0); s1 = fmaf(r1, wa[q].w, s1);
            s0 = fmaf(r2, wb[q].x, s0); s1 = fmaf(r2, wb[q].y, s1);
            s0 = fmaf(r3, wb[q].z, s0); s1 = fmaf(r3, wb[q].w, s1);
        }
        #pragma unroll
        for (int d = 1; d < 16; d <<= 1) {   // within 16-lane group (d<16)
            s0 += __shfl_xor(s0, d);
            s1 += __shfl_xor(s1, d);
        }
        if (t == 0) {
            float S0 = s0 + bb0, S1 = s1 + bb1;
            Sout[jp] = fmaxf(S0, S1) + log1pf(__expf(-fabsf(S0 - S1)));
        }
    }
}

// ---------------- Kernel 3: per-batch DP (R0 verbatim)
__device__ __forceinline__ int tri_base(int i) { return (i * (81 - i)) >> 1; }
#define BIDX(i, j) (tri_base(i) + ((j) - (i) - 1))

constexpr int soff(int W) {
    int s = 0;
    for (int v = 2; v < W; ++v) s += (N1 - v) * (v - 1);
    return s;
}
constexpr int pick_T(int m, int nj) {
    int T = 1;
    while (T < 16 && m * (T * 2) <= DPB && T < nj) T *= 2;
    return T;
}

template<int W>
__device__ __forceinline__ void dp_step(float* __restrict__ Btri,
                                        const float* __restrict__ Sl, int tid)
{
    constexpr int m    = N1 - W;
    constexpr int nj   = W - 1;
    constexpr int T    = pick_T(m, nj);
    constexpr int CH   = (nj + T - 1) / T;
    constexpr int base = soff(W);

    if (tid < m * T) {
        const int i = tid / T;
        const int h = tid % T;
        const int k = i + W;

        float g[CH];
        #pragma unroll
        for (int q = 0; q < CH; ++q) {
            int jp = h + q * T;
            bool live = (q < CH - 1) || (jp < nj);
            int jj = live ? jp : 0;
            float v = Sl[base + i * nj + jj]
                    + Btri[BIDX(i, i + 1 + jj)]
                    + Btri[BIDX(i + 1 + jj, k)];
            g[q] = live ? v : MNEG;
        }
        float mx = g[0];
        #pragma unroll
        for (int q = 1; q < CH; ++q) mx = fmaxf(mx, g[q]);
        float s = 0.f;
        #pragma unroll
        for (int q = 0; q < CH; ++q) s += __expf(g[q] - mx);
        #pragma unroll
        for (int d = 1; d < T; d <<= 1) {
            float mo = __shfl_xor(mx, d);
            float so = __shfl_xor(s, d);
            float nm = fmaxf(mx, mo);
            s = s * __expf(mx - nm) + so * __expf(mo - nm);
            mx = nm;
        }
        if (h == 0)
            Btri[BIDX(i, k)] = mx + __logf(s);
    }
    __syncthreads();
}

template<int W>
__device__ __forceinline__ void dp_from(float* __restrict__ Btri,
                                        const float* __restrict__ Sl, int tid)
{
    dp_step<W>(Btri, Sl, tid);
    if constexpr (W + 1 <= N_TOK) dp_from<W + 1>(Btri, Sl, tid);
}

__global__ __launch_bounds__(DPB) void k_dp(
    const float* __restrict__ Sg, const int* __restrict__ lengths,
    float* __restrict__ out)
{
    __shared__ __align__(16) float Sl[NTRI];
    __shared__ float Btri[820];
    const int tid = threadIdx.x;
    const int b   = blockIdx.x;

    const float4* src = (const float4*)(Sg + b * NTRI);
    float4* dst = (float4*)Sl;
    for (int x = tid; x < NTRI / 4; x += DPB) dst[x] = src[x];
    if (tid < N_TOK) Btri[tri_base(tid)] = 0.f;
    __syncthreads();

    dp_from<2>(Btri, Sl, tid);

    if (tid == 0) {
        int L = lengths[b];
        out[b] = Btri[BIDX(0, L)];
    }
}

extern "C" void kernel_launch(void* const* d_in, const int* in_sizes, int n_in,
                              void* d_out, int out_size, void* d_ws, size_t ws_size,
                              hipStream_t stream)
{
    const float* enc = (const float*)d_in[0];
    const float* W1  = (const float*)d_in[1];
    const float* b1  = (const float*)d_in[2];
    const float* W2  = (const float*)d_in[3];
    const float* b2  = (const float*)d_in[4];
    const int* lengths = (const int*)d_in[5];

    float* ws = (float*)d_ws;
    float* P  = ws;
    float* Qb = ws + ROWF;
    float* Dd = ws + 2 * ROWF;
    float* S  = ws + 3 * ROWF;

    k_proj<<<dim3(N1), dim3(1024), 0, stream>>>(enc, W1, b1, P, Qb, Dd);
    k_score<<<dim3(NPTASK / 4), dim3(256), 0, stream>>>(P, Qb, Dd, W2, b2, S);
    k_dp<<<dim3(BS), dim3(DPB), 0, stream>>>(S, lengths, (float*)d_out);
}

// Round 13
// 115.025 us; speedup vs baseline: 3.9088x; 1.0760x over previous
//
#include <hip/hip_runtime.h>
#include <math.h>

#define N_TOK 40
#define N1    41      // N_TOK + 1
#define BS    8
#define DD    256     // D
#define HH    256     // H
#define NTRI  10660   // C(41,3)
#define NPAIR 780     // pairs (i,k) with k-i>=2
#define NPTASK (NPAIR * BS)   // 6240 tasks, one WAVE each
#define ROWF  (BS * N1 * HH)  // 83968 floats per [b][t][h] array
#define MNEG  (-1e38f)
#define DPB   256

// ---------------- Kernel 1: projections, LDS-staged W1 slab.
// R12 ledger: proj(R9 form) ~34 µs = L2->L1 redundancy bound — each block
// re-streamed the same 512 KB W1 4x (once per b-pair wave-set) through a
// 32 KB L1 (~2 MB/CU at ~32 B/cyc ~ 27 µs). Fix (Guideline 3): 164 blocks
// (t x h-quarter); each stages its 64-col W1 slab ONCE in LDS (w1T[512][64],
// 128 KB, lane-consecutive -> conflict-free) + enc rows (8 KB), then runs
// the identical ascending-d fmaf chain fed from LDS. W1 crosses L2->L1
// exactly once per block. Values/order/epilogue verbatim -> P/Qb/Dd
// bitwise identical.
__global__ __launch_bounds__(256) void k_proj(
    const float* __restrict__ enc, const float* __restrict__ W1,
    const float* __restrict__ b1v,
    float* __restrict__ P, float* __restrict__ Qb, float* __restrict__ Dd)
{
    const int blk  = blockIdx.x;       // 0..163
    const int t    = blk >> 2;         // 0..40
    const int hq   = blk & 3;          // h-quarter
    const int tid  = threadIdx.x;
    const int lane = tid & 63;
    const int pr   = tid >> 6;         // 0..3 (wave index = b-pair)

    __shared__ float w1T[512][64];     // 128 KB: w1T[r][hl] = W1[r*256+hq*64+hl]
    __shared__ float e[BS][DD];        // 8 KB

    // stage W1 slab: wave pr covers rows r = pr, pr+4, ... (coalesced 256 B
    // global reads; LDS writes lane-consecutive -> conflict-free)
    #pragma unroll 8
    for (int r = pr; r < 512; r += 4)
        w1T[r][lane] = W1[(r << 8) + (hq << 6) + lane];
    // stage enc rows for this t (8 rows x 256)
    for (int x = tid; x < BS * DD; x += 256)
        e[x >> 8][x & 255] = enc[(t * BS + (x >> 8)) * DD + (x & 255)];
    __syncthreads();

    const int h  = (hq << 6) + lane;
    const int bA = 2 * pr, bB = 2 * pr + 1;

    float a0 = 0.f, c0 = 0.f, a1 = 0.f, c1 = 0.f;
    #pragma unroll 8
    for (int d = 0; d < DD; ++d) {
        float wp = w1T[d][lane];        // lanes consecutive: conflict-free
        float wq = w1T[256 + d][lane];
        float e0 = e[bA][d];            // wave-uniform: broadcast
        float e1 = e[bB][d];
        a0 = fmaf(e0, wp, a0); c0 = fmaf(e0, wq, c0);
        a1 = fmaf(e1, wp, a1); c1 = fmaf(e1, wq, c1);
    }

    const float bb = b1v[h];
    const int iA = ((bA * N1) + t) * HH + h;
    const int iB = ((bB * N1) + t) * HH + h;
    P[iA]  = a0;          P[iB]  = a1;
    Qb[iA] = c0 + bb;     Qb[iB] = c1 + bb;
    Dd[iA] = a0 - c0;     Dd[iB] = a1 - c1;
}

// ---------------- Kernel 2: scores — one wave per (pair,b) task (R12 verbatim)
__global__ __launch_bounds__(256) void k_score(
    const float* __restrict__ P, const float* __restrict__ Qb,
    const float* __restrict__ Dd, const float* __restrict__ W2,
    const float* __restrict__ b2, float* __restrict__ S)
{
    const int task = blockIdx.x * 4 + (threadIdx.x >> 6);  // one wave per task
    const int lane = threadIdx.x & 63;
    const int js   = lane >> 4;      // j-slice 0..3
    const int t    = lane & 15;      // h-chunk

    const int p = task >> 3;         // pair index, w descending
    const int b = task & 7;

    int c = (int)((sqrtf(8.f * (float)p + 1.f) - 1.f) * 0.5f);
    while ((c + 1) * (c + 2) / 2 <= p) ++c;
    while (c * (c + 1) / 2 > p) --c;
    const int w    = 40 - c;
    const int i    = p - c * (c + 1) / 2;
    const int k    = i + w;
    const int nj   = w - 1;
    const int n2   = w - 2;
    const int base = n2 * (n2 + 1) * (119 - 2 * n2) / 6;   // == soff(w)

    const float4* Pr  = (const float4*)(P  + ((b * N1 + i) << 8)) + t * 4;
    const float4* Qr  = (const float4*)(Qb + ((b * N1 + k) << 8)) + t * 4;
    const float4* W2r = (const float4*)(W2) + t * 8;

    float4 pp[4], qq[4], wa[4], wb[4];
    #pragma unroll
    for (int q = 0; q < 4; ++q) {
        pp[q] = Pr[q]; qq[q] = Qr[q];
        wa[q] = W2r[q * 2]; wb[q] = W2r[q * 2 + 1];
    }
    const float bb0 = b2[0], bb1 = b2[1];
    float* Sout = S + b * NTRI + base + i * nj;

    for (int jp = js; jp < nj; jp += 4) {
        const float4* Drow =
            (const float4*)(Dd + ((b * N1 + i + 1 + jp) << 8)) + t * 4;
        float s0 = 0.f, s1 = 0.f;
        #pragma unroll
        for (int q = 0; q < 4; ++q) {
            float4 dd = Drow[q];
            float r0 = fmaxf(dd.x + qq[q].x - pp[q].x, 0.f);
            float r1 = fmaxf(dd.y + qq[q].y - pp[q].y, 0.f);
            float r2 = fmaxf(dd.z + qq[q].z - pp[q].z, 0.f);
            float r3 = fmaxf(dd.w + qq[q].w - pp[q].w, 0.f);
            s0 = fmaf(r0, wa[q].x, s0); s1 = fmaf(r0, wa[q].y, s1);
            s0 = fmaf(r1, wa[q].z, s0); s1 = fmaf(r1, wa[q].w, s1);
            s0 = fmaf(r2, wb[q].x, s0); s1 = fmaf(r2, wb[q].y, s1);
            s0 = fmaf(r3, wb[q].z, s0); s1 = fmaf(r3, wb[q].w, s1);
        }
        #pragma unroll
        for (int d = 1; d < 16; d <<= 1) {   // within 16-lane group
            s0 += __shfl_xor(s0, d);
            s1 += __shfl_xor(s1, d);
        }
        if (t == 0) {
            float S0 = s0 + bb0, S1 = s1 + bb1;
            Sout[jp] = fmaxf(S0, S1) + log1pf(__expf(-fabsf(S0 - S1)));
        }
    }
}

// ---------------- Kernel 3: per-batch DP (R0 verbatim)
__device__ __forceinline__ int tri_base(int i) { return (i * (81 - i)) >> 1; }
#define BIDX(i, j) (tri_base(i) + ((j) - (i) - 1))

constexpr int soff(int W) {
    int s = 0;
    for (int v = 2; v < W; ++v) s += (N1 - v) * (v - 1);
    return s;
}
constexpr int pick_T(int m, int nj) {
    int T = 1;
    while (T < 16 && m * (T * 2) <= DPB && T < nj) T *= 2;
    return T;
}

template<int W>
__device__ __forceinline__ void dp_step(float* __restrict__ Btri,
                                        const float* __restrict__ Sl, int tid)
{
    constexpr int m    = N1 - W;
    constexpr int nj   = W - 1;
    constexpr int T    = pick_T(m, nj);
    constexpr int CH   = (nj + T - 1) / T;
    constexpr int base = soff(W);

    if (tid < m * T) {
        const int i = tid / T;
        const int h = tid % T;
        const int k = i + W;

        float g[CH];
        #pragma unroll
        for (int q = 0; q < CH; ++q) {
            int jp = h + q * T;
            bool live = (q < CH - 1) || (jp < nj);
            int jj = live ? jp : 0;
            float v = Sl[base + i * nj + jj]
                    + Btri[BIDX(i, i + 1 + jj)]
                    + Btri[BIDX(i + 1 + jj, k)];
            g[q] = live ? v : MNEG;
        }
        float mx = g[0];
        #pragma unroll
        for (int q = 1; q < CH; ++q) mx = fmaxf(mx, g[q]);
        float s = 0.f;
        #pragma unroll
        for (int q = 0; q < CH; ++q) s += __expf(g[q] - mx);
        #pragma unroll
        for (int d = 1; d < T; d <<= 1) {
            float mo = __shfl_xor(mx, d);
            float so = __shfl_xor(s, d);
            float nm = fmaxf(mx, mo);
            s = s * __expf(mx - nm) + so * __expf(mo - nm);
            mx = nm;
        }
        if (h == 0)
            Btri[BIDX(i, k)] = mx + __logf(s);
    }
    __syncthreads();
}

template<int W>
__device__ __forceinline__ void dp_from(float* __restrict__ Btri,
                                        const float* __restrict__ Sl, int tid)
{
    dp_step<W>(Btri, Sl, tid);
    if constexpr (W + 1 <= N_TOK) dp_from<W + 1>(Btri, Sl, tid);
}

__global__ __launch_bounds__(DPB) void k_dp(
    const float* __restrict__ Sg, const int* __restrict__ lengths,
    float* __restrict__ out)
{
    __shared__ __align__(16) float Sl[NTRI];
    __shared__ float Btri[820];
    const int tid = threadIdx.x;
    const int b   = blockIdx.x;

    const float4* src = (const float4*)(Sg + b * NTRI);
    float4* dst = (float4*)Sl;
    for (int x = tid; x < NTRI / 4; x += DPB) dst[x] = src[x];
    if (tid < N_TOK) Btri[tri_base(tid)] = 0.f;
    __syncthreads();

    dp_from<2>(Btri, Sl, tid);

    if (tid == 0) {
        int L = lengths[b];
        out[b] = Btri[BIDX(0, L)];
    }
}

extern "C" void kernel_launch(void* const* d_in, const int* in_sizes, int n_in,
                              void* d_out, int out_size, void* d_ws, size_t ws_size,
                              hipStream_t stream)
{
    const float* enc = (const float*)d_in[0];
    const float* W1  = (const float*)d_in[1];
    const float* b1  = (const float*)d_in[2];
    const float* W2  = (const float*)d_in[3];
    const float* b2  = (const float*)d_in[4];
    const int* lengths = (const int*)d_in[5];

    float* ws = (float*)d_ws;
    float* P  = ws;
    float* Qb = ws + ROWF;
    float* Dd = ws + 2 * ROWF;
    float* S  = ws + 3 * ROWF;

    k_proj<<<dim3(164), dim3(256), 0, stream>>>(enc, W1, b1, P, Qb, Dd);
    k_score<<<dim3(NPTASK / 4), dim3(256), 0, stream>>>(P, Qb, Dd, W2, b2, S);
    k_dp<<<dim3(BS), dim3(DPB), 0, stream>>>(S, lengths, (float*)d_out);
}